// Round 7
// baseline (78.343 us; speedup 1.0000x reference)
//
#include <hip/hip_runtime.h>
#include <stdint.h>

#define BATCH     10000
#define NUM_TREES 1000
#define NUM_NODES 511
#define NFEAT     256
#define DEPTH     8
#define FLAT_NODES (NUM_TREES * NUM_NODES)

// ---------------- 2-level fused record layout in d_ws ----------------
// Implicit depth-8 tree. Records exist at even depths {0,2,4,6}:
//   rec = {f32 thr_p, f32 thr_l, f32 thr_r, u32 f_p|f_l<<8|f_r<<16}
// rec index = EBASE[d/2] + local, EBASE = {0,1,5,21}; 85 recs = 1360 B/tree.
// One b128 read + 2 compares descends 2 levels: local' = 4*local + 2c0 + c1.
// Leaf (depth 8): vleaf[local] per tree (256 f32 = 1024 B).
#define TREE_BYTES 1360
#define VLEAF_OFF  ((size_t)NUM_TREES * TREE_BYTES)          // 1,360,000
#define WS_NEEDED  (VLEAF_OFF + (size_t)NUM_TREES * 256 * 4) // 2,384,000

// ---------------- traverse geometry (2 blocks/CU) ----------------
#define BT 32            // batch rows per block
#define TT 32            // trees per block
#define NTHREADS 512     // 8 waves
#define XS_BYTES  (NFEAT * BT * 4)               // 32768, [feat][32] swizzled
#define NS_BYTES  (TT * TREE_BYTES)              // 43520
#define SH_BYTES  (XS_BYTES + NS_BYTES)          // 76288 -> 2 blocks/CU
#define NCHUNK    (NS_BYTES / 16)                // 2720 uint4 chunks
#define PREF      ((NCHUNK + NTHREADS - 1) / NTHREADS)   // 6
#define OUT_LD    (TT + 1)                       // 33

// ================= prepack: BFS-unroll into 2-level records =================
__global__ __launch_bounds__(256)
void unroll_kernel(const float* __restrict__ thr,
                   const int* __restrict__ feats,
                   const int* __restrict__ lefts,
                   const int* __restrict__ rights,
                   const float* __restrict__ values,
                   unsigned char* __restrict__ ws) {
  __shared__ uint16_t n_s[4][512];
  const int wv = threadIdx.x >> 6, lane = threadIdx.x & 63;
  const int tree = blockIdx.x * 4 + wv;          // grid=250 -> always < 1000
  const int base = tree * NUM_NODES;
  uint16_t* n = n_s[wv];
  uint4* rec   = (uint4*)(ws + (size_t)tree * TREE_BYTES);
  float* vleaf = (float*)(ws + VLEAF_OFF + (size_t)tree * 1024);

  if (lane == 0) n[0] = 0;
  __syncthreads();
  const int EBASE[4] = {0, 1, 5, 21};
  #pragma unroll
  for (int d = 0; d < 8; ++d) {
    const int lvl = (1 << d) - 1, cnt = 1 << d;
    for (int i = lane; i < cnt; i += 64) {
      int p  = lvl + i;
      int np = n[p];
      int nl = lefts[base + np], nr = rights[base + np];
      n[2 * p + 1] = (uint16_t)nl;
      n[2 * p + 2] = (uint16_t)nr;
      if ((d & 1) == 0) {
        uint32_t f3 = (uint32_t)feats[base + np] |
                      ((uint32_t)feats[base + nl] << 8) |
                      ((uint32_t)feats[base + nr] << 16);
        rec[EBASE[d >> 1] + i] =
            make_uint4(__float_as_uint(thr[base + np]),
                       __float_as_uint(thr[base + nl]),
                       __float_as_uint(thr[base + nr]), f3);
      }
    }
    __syncthreads();
  }
  #pragma unroll
  for (int i = lane; i < 256; i += 64)
    vleaf[i] = values[base + n[255 + i]];
}

// ================= main traversal =================
__global__ __launch_bounds__(NTHREADS, 4)   // 4 waves/EU = 2 blocks/CU
void traverse32(const float* __restrict__ x,
                const unsigned char* __restrict__ ws,
                float* __restrict__ out) {
  extern __shared__ unsigned char smem[];
  float* x_s = (float*)smem;                     // [256][32] swizzled
  unsigned char* nodes = smem + XS_BYTES;        // 32 trees * 1360 B
  float* out_s = (float*)nodes;                  // aliased after traversal

  const int tid  = threadIdx.x;
  const int wid  = tid >> 6;                     // 0..7
  const int lane = tid & 63;
  const int row  = lane & 31;                    // batch row within tile
  const int th   = lane >> 5;                    // tree-half select
  const int b0   = blockIdx.y * BT;
  const int t0   = blockIdx.x * TT;

  // ---- issue x loads (4 float4/thread: 32 rows x 64 cols) ----
  const float4* xg = (const float4*)x;
  float4 xv[4];
  #pragma unroll
  for (int p = 0; p < 4; ++p) {
    int i = tid + p * NTHREADS;
    int r = i >> 6, c = i & 63;
    int gb = b0 + r;
    xv[p] = (gb < BATCH) ? xg[gb * 64 + c] : make_float4(0.f, 0.f, 0.f, 0.f);
  }
  // ---- issue node-region loads (linear 42.5 KB; reads past tree 1000 stay
  //      inside ws (vleaf region) and are safe: loc bounded, feats masked) ----
  const uint4* src = (const uint4*)(ws + (size_t)t0 * TREE_BYTES);
  uint4 pf[PREF];
  #pragma unroll
  for (int k = 0; k < PREF; ++k) {
    int fi = tid + k * NTHREADS;
    pf[k] = (fi < NCHUNK) ? src[fi] : make_uint4(0u, 0u, 0u, 0u);
  }
  // ---- write x transposed+swizzled: bank = row ^ (c&31) ----
  #pragma unroll
  for (int p = 0; p < 4; ++p) {
    int i = tid + p * NTHREADS;
    int r = i >> 6, c = i & 63;
    int o = (c << 7) + (r ^ (c & 31));           // feat=4c+k at o + 32*k
    x_s[o]      = xv[p].x;
    x_s[o + 32] = xv[p].y;
    x_s[o + 64] = xv[p].z;
    x_s[o + 96] = xv[p].w;
  }
  // ---- write nodes (b128) ----
  uint4* nd = (uint4*)nodes;
  #pragma unroll
  for (int k = 0; k < PREF; ++k) {
    int fi = tid + k * NTHREADS;
    if (fi < NCHUNK) nd[fi] = pf[k];
  }
  __syncthreads();

  // ---- traverse: wave owns 4 trees; lane-half th picks pair, ILP=2 ----
  const int lt = 4 * wid + 2 * th;
  const unsigned char* nb0 = nodes + (size_t)lt * TREE_BYTES;
  const unsigned char* nb1 = nb0 + TREE_BYTES;
  int loc0 = 0, loc1 = 0;
  #pragma unroll
  for (int it = 0; it < 4; ++it) {
    const int eoff = (it == 0) ? 0 : (it == 1) ? 16 : (it == 2) ? 80 : 336;
    uint4 r0 = *(const uint4*)(nb0 + loc0 * 16 + eoff);
    uint4 r1 = *(const uint4*)(nb1 + loc1 * 16 + eoff);
    int fp0 = r0.w & 255, fl0 = (r0.w >> 8) & 255, fr0 = (r0.w >> 16) & 255;
    int fp1 = r1.w & 255, fl1 = (r1.w >> 8) & 255, fr1 = (r1.w >> 16) & 255;
    float xp0 = x_s[(fp0 << 5) + (row ^ ((fp0 >> 2) & 31))];
    float xl0 = x_s[(fl0 << 5) + (row ^ ((fl0 >> 2) & 31))];
    float xr0 = x_s[(fr0 << 5) + (row ^ ((fr0 >> 2) & 31))];
    float xp1 = x_s[(fp1 << 5) + (row ^ ((fp1 >> 2) & 31))];
    float xl1 = x_s[(fl1 << 5) + (row ^ ((fl1 >> 2) & 31))];
    float xr1 = x_s[(fr1 << 5) + (row ^ ((fr1 >> 2) & 31))];
    bool c00 = (xp0 >= __uint_as_float(r0.x));
    bool c01 = (xp1 >= __uint_as_float(r1.x));
    float xc0 = c00 ? xr0 : xl0;
    float xc1 = c01 ? xr1 : xl1;
    float tc0 = __uint_as_float(c00 ? r0.z : r0.y);
    float tc1 = __uint_as_float(c01 ? r1.z : r1.y);
    loc0 = 4 * loc0 + 2 * (int)c00 + (int)(xc0 >= tc0);
    loc1 = 4 * loc1 + 2 * (int)c01 + (int)(xc1 >= tc1);
  }
  // ---- leaf values from prepacked table (L2-resident, 1 MB) ----
  const float* vl = (const float*)(ws + VLEAF_OFF);
  int g0 = t0 + lt, g1 = g0 + 1;
  int c0 = (g0 < NUM_TREES) ? g0 : 0;
  int c1 = (g1 < NUM_TREES) ? g1 : 0;
  float v0 = vl[(size_t)c0 * 256 + loc0];
  float v1 = vl[(size_t)c1 * 256 + loc1];

  __syncthreads();                     // all node reads done -> alias as out_s
  out_s[row * OUT_LD + lt + 0] = v0;
  out_s[row * OUT_LD + lt + 1] = v1;
  __syncthreads();

  // ---- flush 32x32 tile, coalesced 64 B chunks ----
  #pragma unroll
  for (int k = 0; k < 2; ++k) {
    int rr = tid >> 4, col = (tid & 15) + 16 * k;
    int gb = b0 + rr, gt = t0 + col;
    if (gb < BATCH && gt < NUM_TREES)
      out[(size_t)gb * NUM_TREES + gt] = out_s[rr * OUT_LD + col];
  }
}

// ================= fallback (no-ws path) =================
#define FB_BT 64
#define FB_TT 64
#define FB_TPR 16
#define FB_NROUNDS 4
#define FB_NTHREADS 1024
#define FB_XS (NFEAT * 64 * 4)
#define FB_NSU (FB_TPR * NUM_NODES)
#define FB_NS (FB_NSU * 8)
#define FB_OLD (FB_TT + 1)
#define FB_OS (FB_BT * FB_OLD * 4)
#define FB_SH (FB_XS + FB_NS + FB_OS)
#define FB_PREF ((FB_NSU + FB_NTHREADS - 1) / FB_NTHREADS)

__global__ __launch_bounds__(FB_NTHREADS, 1)
void fb_traverse(const float* __restrict__ x,
                 const float* __restrict__ thrg,
                 const int* __restrict__ featg,
                 const int* __restrict__ leftg,
                 const int* __restrict__ rightg,
                 const float* __restrict__ values,
                 float* __restrict__ out) {
  extern __shared__ unsigned char smem[];
  float* x_s     = (float*)smem;
  uint2* nodes_s = (uint2*)(smem + FB_XS);
  float* out_s   = (float*)(smem + FB_XS + FB_NS);
  const int tid = threadIdx.x, wid = tid >> 6, lane = tid & 63;
  const int b0 = blockIdx.y * FB_BT, t0 = blockIdx.x * FB_TT;
  uint2 pf[FB_PREF];
  auto load_round = [&](int rr) {
    const int gbase = (t0 + rr * FB_TPR) * NUM_NODES;
    #pragma unroll
    for (int k = 0; k < FB_PREF; ++k) {
      int fi = tid + k * FB_NTHREADS;
      uint2 v = make_uint2(0u, 0u);
      if (fi < FB_NSU) {
        int gi = gbase + fi;
        if (gi < FLAT_NODES) {
          uint32_t meta = (uint32_t)featg[gi] | ((uint32_t)leftg[gi] << 8) |
                          ((uint32_t)rightg[gi] << 20);
          v = make_uint2(__float_as_uint(thrg[gi]), meta);
        }
      }
      pf[k] = v;
    }
  };
  auto write_nodes = [&]() {
    #pragma unroll
    for (int k = 0; k < FB_PREF; ++k) {
      int fi = tid + k * FB_NTHREADS;
      if (fi < FB_NSU) nodes_s[fi] = pf[k];
    }
  };
  load_round(0);
  {
    const float4* xg = (const float4*)x;
    #pragma unroll
    for (int p = 0; p < (FB_BT * (NFEAT / 4)) / FB_NTHREADS; ++p) {
      int i = tid + p * FB_NTHREADS;
      int r = i >> 6, c = i & 63;
      int gb = b0 + r;
      float4 v = make_float4(0.f, 0.f, 0.f, 0.f);
      if (gb < BATCH) v = xg[gb * (NFEAT / 4) + c];
      int o = (c << 8) + (r ^ (c & 31));
      x_s[o] = v.x; x_s[o + 64] = v.y; x_s[o + 128] = v.z; x_s[o + 192] = v.w;
    }
  }
  write_nodes();
  __syncthreads();
  for (int r = 0; r < FB_NROUNDS; ++r) {
    if (r + 1 < FB_NROUNDS) load_round(r + 1);
    const uint2* nA = nodes_s + wid * NUM_NODES;
    const int tr0 = t0 + r * FB_TPR;
    const int gta = tr0 + wid;
    const int offA = (gta < NUM_TREES ? gta : 0) * NUM_NODES;
    uint2 na = nA[0];
    float va = 0.f;
    #pragma unroll
    for (int d = 0; d < DEPTH; ++d) {
      int fa = na.y & 0xFF;
      int la = (na.y >> 8) & 0xFFF;
      int ra = (int)(na.y >> 20);
      float xa = x_s[(fa << 6) + (lane ^ ((fa >> 2) & 31))];
      if (d < DEPTH - 1) {
        uint2 nla = nA[la], nra = nA[ra];
        na = (xa >= __uint_as_float(na.x)) ? nra : nla;
      } else {
        float vla = values[offA + la], vra = values[offA + ra];
        va = (xa >= __uint_as_float(na.x)) ? vra : vla;
      }
    }
    out_s[lane * FB_OLD + r * FB_TPR + wid] = va;
    __syncthreads();
    if (r + 1 < FB_NROUNDS) { write_nodes(); __syncthreads(); }
  }
  {
    const int gt = t0 + lane;
    #pragma unroll
    for (int p = 0; p < FB_BT / 16; ++p) {
      int rr = p * 16 + wid;
      int gb = b0 + rr;
      if (gb < BATCH && gt < NUM_TREES)
        out[gb * NUM_TREES + gt] = out_s[rr * FB_OLD + lane];
    }
  }
}

extern "C" void kernel_launch(void* const* d_in, const int* in_sizes, int n_in,
                              void* d_out, int out_size, void* d_ws, size_t ws_size,
                              hipStream_t stream) {
  const float* x          = (const float*)d_in[0];
  const float* thresholds = (const float*)d_in[1];
  const float* values     = (const float*)d_in[2];
  const int*   lefts      = (const int*)d_in[3];
  const int*   rights     = (const int*)d_in[4];
  const int*   features   = (const int*)d_in[5];
  float* out = (float*)d_out;

  if (ws_size >= WS_NEEDED) {
    unsigned char* ws = (unsigned char*)d_ws;
    unroll_kernel<<<NUM_TREES / 4, 256, 0, stream>>>(
        thresholds, features, lefts, rights, values, ws);
    hipFuncSetAttribute(reinterpret_cast<const void*>(traverse32),
                        hipFuncAttributeMaxDynamicSharedMemorySize, SH_BYTES);
    dim3 grid((NUM_TREES + TT - 1) / TT, (BATCH + BT - 1) / BT);   // 32 x 313
    traverse32<<<grid, NTHREADS, SH_BYTES, stream>>>(x, ws, out);
  } else {
    hipFuncSetAttribute(reinterpret_cast<const void*>(fb_traverse),
                        hipFuncAttributeMaxDynamicSharedMemorySize, FB_SH);
    dim3 grid((NUM_TREES + FB_TT - 1) / FB_TT, (BATCH + FB_BT - 1) / FB_BT);
    fb_traverse<<<grid, FB_NTHREADS, FB_SH, stream>>>(
        x, thresholds, features, lefts, rights, values, out);
  }
}